// Round 16
// baseline (426.858 us; speedup 1.0000x reference)
//
#include <hip/hip_runtime.h>
#include <hip/hip_bf16.h>
#include <math.h>

typedef __attribute__((ext_vector_type(8))) short bf16x8;
typedef __attribute__((ext_vector_type(8))) unsigned short u16x8;
typedef __attribute__((ext_vector_type(4))) float f32x4;
typedef __attribute__((ext_vector_type(4))) unsigned short u16x4;

__device__ inline unsigned short f2bf(float f) {
    union { float f; unsigned u; } v; v.f = f;
    unsigned r = (v.u + 0x7fff + ((v.u >> 16) & 1)) >> 16;   // RNE
    return (unsigned short)r;
}
__device__ inline float bf2f(unsigned short u) {
    union { unsigned u; float f; } v; v.u = ((unsigned)u) << 16; return v.f;
}

#define GLL16(gp, lp) __builtin_amdgcn_global_load_lds(                      \
    (const __attribute__((address_space(1))) void*)(gp),                     \
    (__attribute__((address_space(3))) void*)(lp), 16, 0, 0)

// ---------------------------------------------------------------------------
// bf16 MFMA GEMM combining BOTH verified mechanisms:
//  (1) r15: __launch_bounds__(256,4) -> 128-reg cap -> 4 blocks/CU resident
//      (acc 64 + frags 32 + addr ~20 = ~115 regs, fits without spill)
//  (2) r11: 2-phase stage-early double-buffer -> prefetch(t+1) issued BEFORE
//      compute(t); the single per-tile barrier's vmcnt-drain then completes
//      almost immediately (loads had the whole compute phase to land).
// 128x128 tile, BK=32, 4 waves (2x2), per-wave 64x64 = 4x4 frags.
// LDS 2 x 16KB = 32KB -> 4 blocks fit (LDS cap 5, reg cap 4).
// Swizzle involution (c^r^(r>>2))&3 (r10; residual 2-way is free, m136).
// EPI: 0=none 1=+bias 2=+bias+gelu(tanh-approx). OUT_BF: bf16 output.
// ---------------------------------------------------------------------------
template<int EPI, int OUT_BF>
__global__ __launch_bounds__(256, 4) void gemm2ph128(
    const unsigned short* __restrict__ A,
    const unsigned short* __restrict__ Bt,
    const float* __restrict__ bias,
    void* __restrict__ Cout,
    int M, int Nn, int K, int ldc)
{
    __shared__ unsigned char lds[2][16384];     // per buf: A 8KB ++ B 8KB
    const int tid = threadIdx.x;
    const int w = tid >> 6, lane = tid & 63;
    const int lk = lane & 15, lg = lane >> 4;
    const int wr = w >> 1, wc = w & 1;
    const int nbn = Nn >> 7;
    const int nb = gridDim.x;
    int bid = blockIdx.x;
    int swz = (nb & 7) ? bid : (bid & 7) * (nb >> 3) + (bid >> 3);  // XCD swizzle
    const int bm = (swz / nbn) << 7, bn = (swz % nbn) << 7;

    f32x4 acc[4][4] = {};

    auto stage = [&](int buf, int k0) {
        #pragma unroll
        for (int i = 0; i < 4; ++i) {           // 1024 slots of 16B
            int s = tid + i * 256;
            int r = s >> 2, c = s & 3;
            int cs = (c ^ r ^ (r >> 2)) & 3;
            const unsigned short* gp = (r < 128)
                ? A  + (size_t)(bm + r) * K + k0 + cs * 8
                : Bt + (size_t)(bn + (r - 128)) * K + k0 + cs * 8;
            GLL16(gp, &lds[buf][s * 16]);
        }
    };

    const int NT = K >> 5;
    stage(0, 0);
    __syncthreads();                            // prologue drain
    int cur = 0;
    for (int t = 0; t < NT; ++t) {
        if (t + 1 < NT) stage(cur ^ 1, (t + 1) << 5);   // issue-early prefetch
        bf16x8 af[4], bfr[4];
        #pragma unroll
        for (int m = 0; m < 4; ++m) {
            int row = wr * 64 + m * 16 + lk;
            int sl = (lg ^ row ^ (row >> 2)) & 3;
            af[m] = *(const bf16x8*)&lds[cur][row * 64 + sl * 16];
        }
        #pragma unroll
        for (int n = 0; n < 4; ++n) {
            int row = wc * 64 + n * 16 + lk;
            int sl = (lg ^ row ^ (row >> 2)) & 3;
            bfr[n] = *(const bf16x8*)&lds[cur][8192 + row * 64 + sl * 16];
        }
        #pragma unroll
        for (int m = 0; m < 4; ++m)
            #pragma unroll
            for (int n = 0; n < 4; ++n)
                acc[m][n] = __builtin_amdgcn_mfma_f32_16x16x32_bf16(af[m], bfr[n], acc[m][n], 0, 0, 0);
        __syncthreads();                        // all reads of cur done; buf^1 landed
        cur ^= 1;
    }

    #pragma unroll
    for (int m = 0; m < 4; ++m) {
        int row = bm + wr * 64 + m * 16 + lg * 4;
        #pragma unroll
        for (int n = 0; n < 4; ++n) {
            int col = bn + wc * 64 + n * 16 + lk;
            #pragma unroll
            for (int r = 0; r < 4; ++r) {
                float v = acc[m][n][r];
                if (EPI >= 1) v += bias[col];
                if (EPI == 2) {
                    float u = v * 0.7978845608f * (1.0f + 0.044715f * v * v);
                    v = v / (1.0f + __expf(-2.0f * u));
                }
                if (OUT_BF)
                    ((unsigned short*)Cout)[(size_t)(row + r) * ldc + col] = f2bf(v);
                else
                    ((float*)Cout)[(size_t)(row + r) * ldc + col] = v;
            }
        }
    }
}

// ---------------------------------------------------------------------------
__global__ __launch_bounds__(256) void cvt_bf16(
    const float* __restrict__ src, unsigned short* __restrict__ dst, int n)
{
    int i = (blockIdx.x * 256 + threadIdx.x) * 4;
    if (i < n) {
        float4 v = *(const float4*)(src + i);
        u16x4 o = { f2bf(v.x), f2bf(v.y), f2bf(v.z), f2bf(v.w) };
        *(u16x4*)(dst + i) = o;
    }
}

// ---------------------------------------------------------------------------
__global__ __launch_bounds__(256) void transpose_cvt(
    const float* __restrict__ src, unsigned short* __restrict__ dst, int R, int Cc)
{
    __shared__ float t[32][33];
    const int bc = blockIdx.x * 32, br = blockIdx.y * 32;
    const int tx = threadIdx.x & 31, ty = threadIdx.x >> 5;
    #pragma unroll
    for (int i = 0; i < 4; ++i)
        t[ty + i * 8][tx] = src[(size_t)(br + ty + i * 8) * Cc + bc + tx];
    __syncthreads();
    #pragma unroll
    for (int i = 0; i < 4; ++i)
        dst[(size_t)(bc + ty + i * 8) * R + br + tx] = f2bf(t[tx][ty + i * 8]);
}

// ---------------------------------------------------------------------------
__global__ __launch_bounds__(256) void drofe_bf(
    const unsigned short* __restrict__ QK, unsigned short* __restrict__ Qo,
    unsigned short* __restrict__ Ko,
    const float* __restrict__ freqband, const float* __restrict__ demo, int N)
{
    const float PI_F = 3.14159265358979323846f;
    int idx = blockIdx.x * 256 + threadIdx.x;
    int col2 = idx & 511;
    int row  = idx >> 9;
    int n = row & (N - 1), b = row >> 10;
    int i  = col2 & 31;
    int ii = (i < 16) ? i : i - 16;
    float fb = (i < 16) ? freqband[n * 2 + 0] : freqband[n * 2 + 1];
    float freq = (1.0f + (float)ii * (4.0f / 15.0f)) * PI_F;
    float ang = fb * freq;
    float cv = cosf(ang), sv = sinf(ang);
    float ca = cv * demo[b * 2 + 0];
    float sg = sv * demo[b * 2 + 1];
    const unsigned* qk = (const unsigned*)(QK + (size_t)row * 2048);
    unsigned qu = qk[col2], ku = qk[512 + col2];
    float qe = bf2f((unsigned short)qu), qo_ = bf2f((unsigned short)(qu >> 16));
    float ke = bf2f((unsigned short)ku), ko_ = bf2f((unsigned short)(ku >> 16));
    const float s8 = 0.125f;
    unsigned qres = (unsigned)f2bf((qe * ca - qo_ * sg) * s8)
                  | ((unsigned)f2bf((qo_ * ca + qe * sg) * s8) << 16);
    unsigned kres = (unsigned)f2bf(ke * ca - ko_ * sg)
                  | ((unsigned)f2bf(ko_ * ca + ke * sg) << 16);
    ((unsigned*)Qo)[(size_t)row * 512 + col2] = qres;
    ((unsigned*)Ko)[(size_t)row * 512 + col2] = kres;
}

// ---------------------------------------------------------------------------
// Flash attention, swapped-operand (r14-verified) + r16: T13 defer-max
// (skip O-rescale when __all(pmax - m_run <= 8), wave-uniform branch) and
// T5 setprio(1) around both MFMA clusters (catalog: +4-7% attn).
// ---------------------------------------------------------------------------
__global__ __launch_bounds__(256) void attn_mfma(
    const unsigned short* __restrict__ Q, const unsigned short* __restrict__ K,
    const unsigned short* __restrict__ V, unsigned short* __restrict__ O,
    int B, int H, int N)
{
    __shared__ unsigned short Ks[64 * 64];
    __shared__ unsigned short Vt[64 * 72];
    __shared__ unsigned short Ps[4][16 * 72];

    const int bi = blockIdx.x;
    const int bh = (bi & 7) + 8 * ((bi >> 3) & 15);
    const int q0 = (bi >> 7) * 64;
    const int b = bh >> 4, h = bh & 15;
    const int tid = threadIdx.x;
    const int w = tid >> 6, lane = tid & 63;
    const int lg = lane >> 4, lk = lane & 15;

    bf16x8 qf[2];
    {
        const unsigned short* qrow = Q + (size_t)(b * N + q0 + w * 16 + lk) * 1024 + h * 64;
        qf[0] = *(const bf16x8*)(qrow + lg * 8);
        qf[1] = *(const bf16x8*)(qrow + 32 + lg * 8);
    }

    f32x4 o[4] = {};
    float m_run = -INFINITY, l_run = 0.f;

    for (int t0 = 0; t0 < N; t0 += 64) {
        const size_t kvbase = (size_t)(b * N + t0) * 1024 + h * 64;
        #pragma unroll
        for (int it = 0; it < 2; ++it) {
            int s = it * 256 + tid;
            int row = s >> 3, cb = (s & 7) << 4;
            int dby = cb ^ ((row & 7) << 4);
            GLL16(K + kvbase + (size_t)row * 1024 + (dby >> 1), &Ks[s * 8]);
        }
        {
            int c = tid >> 5, k0 = (tid & 31) * 2;
            const unsigned short* vp = V + kvbase + (size_t)k0 * 1024 + c * 8;
            u16x8 va = *(const u16x8*)vp;
            u16x8 vb = *(const u16x8*)(vp + 1024);
            #pragma unroll
            for (int j = 0; j < 8; ++j) {
                unsigned val = (unsigned)va[j] | ((unsigned)vb[j] << 16);
                *(unsigned*)&Vt[(c * 8 + j) * 72 + k0] = val;
            }
        }
        __syncthreads();

        f32x4 s4[4];
        __builtin_amdgcn_s_setprio(1);
        #pragma unroll
        for (int sub = 0; sub < 4; ++sub) {
            f32x4 acc = {0.f, 0.f, 0.f, 0.f};
            #pragma unroll
            for (int kh = 0; kh < 2; ++kh) {
                int cc = (kh * 64 + lg * 16) ^ ((lk & 7) << 4);
                bf16x8 kf = *(const bf16x8*)&Ks[(sub * 16 + lk) * 64 + (cc >> 1)];
                acc = __builtin_amdgcn_mfma_f32_16x16x32_bf16(kf, qf[kh], acc, 0, 0, 0);
            }
            s4[sub] = acc;
        }
        __builtin_amdgcn_s_setprio(0);

        // lane-local row max (q = lk spread over lanes lk,lk+16,lk+32,lk+48)
        float pmax = -INFINITY;
        #pragma unroll
        for (int sub = 0; sub < 4; ++sub)
            #pragma unroll
            for (int r = 0; r < 4; ++r) pmax = fmaxf(pmax, s4[sub][r]);
        pmax = fmaxf(pmax, __shfl_xor(pmax, 16));
        pmax = fmaxf(pmax, __shfl_xor(pmax, 32));

        // T13 defer-max: rescale only when some row grew by > 8
        if (!__all(pmax - m_run <= 8.0f)) {
            float mn = fmaxf(m_run, pmax);
            float corr = __expf(m_run - mn);
            m_run = mn;
            l_run *= corr;
            #pragma unroll
            for (int ds = 0; ds < 4; ++ds)
                #pragma unroll
                for (int r = 0; r < 4; ++r) o[ds][r] *= corr;
        }

        float psum = 0.f;
        unsigned pw[4][2];
        #pragma unroll
        for (int sub = 0; sub < 4; ++sub) {
            float p0 = __expf(s4[sub][0] - m_run);
            float p1 = __expf(s4[sub][1] - m_run);
            float p2 = __expf(s4[sub][2] - m_run);
            float p3 = __expf(s4[sub][3] - m_run);
            psum += (p0 + p1) + (p2 + p3);
            pw[sub][0] = (__float_as_uint(p0) >> 16) | (__float_as_uint(p1) & 0xffff0000u);
            pw[sub][1] = (__float_as_uint(p2) >> 16) | (__float_as_uint(p3) & 0xffff0000u);
        }
        psum += __shfl_xor(psum, 16);
        psum += __shfl_xor(psum, 32);
        l_run += psum;
        #pragma unroll
        for (int sub = 0; sub < 4; ++sub) {
            *(unsigned*)&Ps[w][lk * 72 + sub * 16 + lg * 4]     = pw[sub][0];
            *(unsigned*)&Ps[w][lk * 72 + sub * 16 + lg * 4 + 2] = pw[sub][1];
        }
        asm volatile("s_waitcnt lgkmcnt(0)" ::: "memory");   // per-wave P RAW

        __builtin_amdgcn_s_setprio(1);
        #pragma unroll
        for (int kh = 0; kh < 2; ++kh) {
            bf16x8 pf = *(const bf16x8*)&Ps[w][lk * 72 + kh * 32 + lg * 8];
            #pragma unroll
            for (int ds = 0; ds < 4; ++ds) {
                bf16x8 vf = *(const bf16x8*)&Vt[(ds * 16 + lk) * 72 + kh * 32 + lg * 8];
                o[ds] = __builtin_amdgcn_mfma_f32_16x16x32_bf16(vf, pf, o[ds], 0, 0, 0);
            }
        }
        __builtin_amdgcn_s_setprio(0);
        __syncthreads();
    }

    {
        unsigned short* orow = O + (size_t)(b * N + q0 + w * 16 + lk) * 1024 + h * 64;
        float rinv = 1.0f / l_run;
        #pragma unroll
        for (int ds = 0; ds < 4; ++ds) {
            u16x4 pk = { f2bf(o[ds][0] * rinv), f2bf(o[ds][1] * rinv),
                         f2bf(o[ds][2] * rinv), f2bf(o[ds][3] * rinv) };
            *(u16x4*)(orow + ds * 16 + lg * 4) = pk;
        }
    }
}

// ---------------------------------------------------------------------------
// Fused residual + LayerNorm: out = LN(x + gamma*bf2f(y)) * w + b
// ---------------------------------------------------------------------------
__global__ __launch_bounds__(256) void ln_res_kernel(
    const float* __restrict__ x, const unsigned short* __restrict__ y,
    const float* __restrict__ gamma, const float* __restrict__ w,
    const float* __restrict__ bia, float* __restrict__ out,
    unsigned short* __restrict__ out_bf, int C)
{
    const int row = blockIdx.x;
    __shared__ float buf[1024];
    __shared__ float red[8];
    const size_t base = (size_t)row * C;
    float s = 0.f, ss = 0.f;
    for (int c = threadIdx.x; c < C; c += 256) {
        float v = x[base + c] + gamma[c] * bf2f(y[base + c]);
        buf[c] = v; s += v; ss += v * v;
    }
    #pragma unroll
    for (int msk = 1; msk < 64; msk <<= 1) { s += __shfl_xor(s, msk); ss += __shfl_xor(ss, msk); }
    int wv = threadIdx.x >> 6, lane = threadIdx.x & 63;
    if (lane == 0) { red[wv * 2] = s; red[wv * 2 + 1] = ss; }
    __syncthreads();
    if (threadIdx.x == 0) {
        float S = 0.f, SS = 0.f;
        #pragma unroll
        for (int i = 0; i < 4; ++i) { S += red[2 * i]; SS += red[2 * i + 1]; }
        red[0] = S; red[1] = SS;
    }
    __syncthreads();
    float mu = red[0] / C;
    float var = red[1] / C - mu * mu;
    float rstd = rsqrtf(var + 1e-5f);
    for (int c = threadIdx.x; c < C; c += 256) {
        float v = (buf[c] - mu) * rstd * w[c] + bia[c];
        out[base + c] = v;
        if (out_bf) out_bf[base + c] = f2bf(v);
    }
}

// ---------------------------------------------------------------------------
extern "C" void kernel_launch(void* const* d_in, const int* in_sizes, int n_in,
                              void* d_out, int out_size, void* d_ws, size_t ws_size,
                              hipStream_t stream)
{
    const float* x      = (const float*)d_in[0];
    const float* demo   = (const float*)d_in[1];
    const float* expl   = (const float*)d_in[2];
    const float* fb     = (const float*)d_in[3];
    const float* w_qkv  = (const float*)d_in[4];
    const float* w_proj = (const float*)d_in[5];
    const float* b_proj = (const float*)d_in[6];
    const float* gamma1 = (const float*)d_in[7];
    const float* gamma2 = (const float*)d_in[8];
    const float* ln1_w  = (const float*)d_in[9];
    const float* ln1_b  = (const float*)d_in[10];
    const float* ln2_w  = (const float*)d_in[11];
    const float* ln2_b  = (const float*)d_in[12];
    const float* w1     = (const float*)d_in[13];
    const float* b1     = (const float*)d_in[14];
    const float* w2     = (const float*)d_in[15];
    const float* b2     = (const float*)d_in[16];
    float* out = (float*)d_out;

    const int B = 8, N = 1024, C = 1024, F = 4096, H = 16;
    const int M = B * N;                        // 8192
    const size_t Mi = 1048576;

    float* ws = (float*)d_ws;
    unsigned short* QKbf = (unsigned short*)ws;              // M x 2048 bf16
    unsigned short* Obf  = (unsigned short*)ws;              // M x 1024 bf16
    unsigned short* H2   = (unsigned short*)ws;              // M x 1024 bf16
    unsigned short* Qbf  = (unsigned short*)(ws + 8 * Mi);   // M x 1024 bf16
    unsigned short* Kbf  = (unsigned short*)(ws + 12 * Mi);
    unsigned short* Vbf  = (unsigned short*)(ws + 16 * Mi);
    unsigned short* Hid  = (unsigned short*)(ws + 8 * Mi);   // M x 4096 bf16
    unsigned short* Ebf  = (unsigned short*)(ws + 24 * Mi);
    unsigned short* Xbf  = (unsigned short*)(ws + 28 * Mi);
    unsigned short* Pb   = (unsigned short*)(ws + 24 * Mi);  // M x 1024 bf16
    float*          X1   = ws + 32 * Mi;                     // M x 1024 f32
    unsigned short* X1bf = (unsigned short*)(ws + 40 * Mi);
    unsigned short* Wt   = (unsigned short*)(ws + 44 * Mi);
    unsigned short* wqkvT  = Wt;                             // [3072][1024]
    unsigned short* wprojT = Wt + (size_t)3145728;           // [1024][1024]
    unsigned short* w1T    = wprojT + (size_t)1048576;       // [4096][1024]
    unsigned short* w2T    = w1T + (size_t)4194304;          // [1024][4096]

    dim3 blk(256);
    const int MC = M * C;

    hipLaunchKernelGGL(cvt_bf16, dim3(MC / 1024), blk, 0, stream, expl, Ebf, MC);
    hipLaunchKernelGGL(cvt_bf16, dim3(MC / 1024), blk, 0, stream, x, Xbf, MC);
    hipLaunchKernelGGL(transpose_cvt, dim3(96, 32), blk, 0, stream, w_qkv, wqkvT, C, 3 * C);
    hipLaunchKernelGGL(transpose_cvt, dim3(32, 32), blk, 0, stream, w_proj, wprojT, C, C);
    hipLaunchKernelGGL(transpose_cvt, dim3(128, 32), blk, 0, stream, w1, w1T, C, F);
    hipLaunchKernelGGL(transpose_cvt, dim3(32, 128), blk, 0, stream, w2, w2T, F, C);

    // QK projection; V projection  [2ph128 + 4 waves/EU]
    hipLaunchKernelGGL((gemm2ph128<0,1>), dim3(64 * 16), blk, 0, stream, Ebf, wqkvT, (const float*)nullptr, (void*)QKbf, M, 2048, C, 2048);
    hipLaunchKernelGGL((gemm2ph128<0,1>), dim3(64 * 8), blk, 0, stream, Xbf, wqkvT + (size_t)2048 * 1024, (const float*)nullptr, (void*)Vbf, M, 1024, C, 1024);

    // drofe: bf16 QK -> rotated bf16 Q (scaled), K
    hipLaunchKernelGGL(drofe_bf, dim3(M * 512 / 256), blk, 0, stream, QKbf, Qbf, Kbf, fb, demo, N);

    // attention -> bf16 O
    hipLaunchKernelGGL(attn_mfma, dim3(B * H * (N / 64)), blk, 0, stream, Qbf, Kbf, Vbf, Obf, B, H, N);

    // output projection -> bf16 Pb
    hipLaunchKernelGGL((gemm2ph128<1,1>), dim3(64 * 8), blk, 0, stream, Obf, wprojT, b_proj, (void*)Pb, M, 1024, C, 1024);

    // residual + LN1 (f32 + bf16)
    hipLaunchKernelGGL(ln_res_kernel, dim3(M), blk, 0, stream, x, Pb, gamma1, ln1_w, ln1_b, X1, X1bf, C);

    // MLP: MLP1 [2ph128, fast gelu], MLP2 [2ph128, K=4096] -> bf16
    hipLaunchKernelGGL((gemm2ph128<2,1>), dim3(64 * 32), blk, 0, stream, X1bf, w1T, b1, (void*)Hid, M, F, C, F);
    hipLaunchKernelGGL((gemm2ph128<1,1>), dim3(64 * 8), blk, 0, stream, Hid, w2T, b2, (void*)H2, M, 1024, F, 1024);

    // residual + LN2 -> out
    hipLaunchKernelGGL(ln_res_kernel, dim3(M), blk, 0, stream, X1, H2, gamma2, ln2_w, ln2_b, out, (unsigned short*)nullptr, C);
}

// Round 17
// 409.003 us; speedup vs baseline: 1.0437x; 1.0437x over previous
//
#include <hip/hip_runtime.h>
#include <hip/hip_bf16.h>
#include <math.h>

typedef __attribute__((ext_vector_type(8))) short bf16x8;
typedef __attribute__((ext_vector_type(8))) unsigned short u16x8;
typedef __attribute__((ext_vector_type(4))) float f32x4;
typedef __attribute__((ext_vector_type(4))) unsigned short u16x4;

__device__ inline unsigned short f2bf(float f) {
    union { float f; unsigned u; } v; v.f = f;
    unsigned r = (v.u + 0x7fff + ((v.u >> 16) & 1)) >> 16;   // RNE
    return (unsigned short)r;
}
__device__ inline float bf2f(unsigned short u) {
    union { unsigned u; float f; } v; v.u = ((unsigned)u) << 16; return v.f;
}

#define GLL16(gp, lp) __builtin_amdgcn_global_load_lds(                      \
    (const __attribute__((address_space(1))) void*)(gp),                     \
    (__attribute__((address_space(3))) void*)(lp), 16, 0, 0)

// ---------------------------------------------------------------------------
// bf16 MFMA GEMM (r15/r16-verified plateau config): 128x128 tile, BK=32,
// 4 waves, 2-phase dbuf stage-early, __launch_bounds__(256,4) -> 16 waves/CU.
// EPI: 0=none 1=+bias 2=+bias+gelu 3=fused drofe (rotate via shfl_xor(1)
// partner + __sincosf; Q cols<1024 scaled 0.125 -> Cout, K cols>=1024 -> Cout2)
// ---------------------------------------------------------------------------
template<int EPI, int OUT_BF>
__global__ __launch_bounds__(256, 4) void gemm2ph128(
    const unsigned short* __restrict__ A,
    const unsigned short* __restrict__ Bt,
    const float* __restrict__ bias,
    void* __restrict__ Cout,
    void* __restrict__ Cout2,
    const float* __restrict__ fbq,
    const float* __restrict__ demo,
    int M, int Nn, int K, int ldc)
{
    __shared__ unsigned char lds[2][16384];     // per buf: A 8KB ++ B 8KB
    const int tid = threadIdx.x;
    const int w = tid >> 6, lane = tid & 63;
    const int lk = lane & 15, lg = lane >> 4;
    const int wr = w >> 1, wc = w & 1;
    const int nbn = Nn >> 7;
    const int nb = gridDim.x;
    int bid = blockIdx.x;
    int swz = (nb & 7) ? bid : (bid & 7) * (nb >> 3) + (bid >> 3);  // XCD swizzle
    const int bm = (swz / nbn) << 7, bn = (swz % nbn) << 7;

    f32x4 acc[4][4] = {};

    auto stage = [&](int buf, int k0) {
        #pragma unroll
        for (int i = 0; i < 4; ++i) {           // 1024 slots of 16B
            int s = tid + i * 256;
            int r = s >> 2, c = s & 3;
            int cs = (c ^ r ^ (r >> 2)) & 3;
            const unsigned short* gp = (r < 128)
                ? A  + (size_t)(bm + r) * K + k0 + cs * 8
                : Bt + (size_t)(bn + (r - 128)) * K + k0 + cs * 8;
            GLL16(gp, &lds[buf][s * 16]);
        }
    };

    const int NT = K >> 5;
    stage(0, 0);
    __syncthreads();                            // prologue drain
    int cur = 0;
    for (int t = 0; t < NT; ++t) {
        if (t + 1 < NT) stage(cur ^ 1, (t + 1) << 5);   // issue-early prefetch
        bf16x8 af[4], bfr[4];
        #pragma unroll
        for (int m = 0; m < 4; ++m) {
            int row = wr * 64 + m * 16 + lk;
            int sl = (lg ^ row ^ (row >> 2)) & 3;
            af[m] = *(const bf16x8*)&lds[cur][row * 64 + sl * 16];
        }
        #pragma unroll
        for (int n = 0; n < 4; ++n) {
            int row = wc * 64 + n * 16 + lk;
            int sl = (lg ^ row ^ (row >> 2)) & 3;
            bfr[n] = *(const bf16x8*)&lds[cur][8192 + row * 64 + sl * 16];
        }
        #pragma unroll
        for (int m = 0; m < 4; ++m)
            #pragma unroll
            for (int n = 0; n < 4; ++n)
                acc[m][n] = __builtin_amdgcn_mfma_f32_16x16x32_bf16(af[m], bfr[n], acc[m][n], 0, 0, 0);
        __syncthreads();                        // reads of cur done; buf^1 landed
        cur ^= 1;
    }

    if (EPI == 3) {
        // fused drofe epilogue: rotate (even,odd) feature pairs.
        const float PI_F = 3.14159265358979323846f;
        const int b_ = bm >> 10;                // 128-row tile fits one batch
        const float age = demo[b_ * 2 + 0], gen = demo[b_ * 2 + 1];
        #pragma unroll
        for (int m = 0; m < 4; ++m) {
            #pragma unroll
            for (int n = 0; n < 4; ++n) {
                int col = bn + wc * 64 + n * 16 + lk;
                int i = (col & 63) >> 1;
                int ii = (i < 16) ? i : i - 16;
                float freq = (1.0f + (float)ii * (4.0f / 15.0f)) * PI_F;
                int fsel = (i >= 16) ? 1 : 0;
                #pragma unroll
                for (int r = 0; r < 4; ++r) {
                    int row = bm + wr * 64 + m * 16 + lg * 4 + r;
                    float val = acc[m][n][r];
                    float par = __shfl_xor(val, 1);
                    int nn = row & 1023;
                    float ang = fbq[nn * 2 + fsel] * freq;
                    float sv, cv;
                    __sincosf(ang, &sv, &cv);
                    float ca = cv * age, sg = sv * gen;
                    float res = (col & 1) ? (val * ca + par * sg)
                                          : (val * ca - par * sg);
                    if (col < 1024)
                        ((unsigned short*)Cout)[(size_t)row * 1024 + col] = f2bf(res * 0.125f);
                    else
                        ((unsigned short*)Cout2)[(size_t)row * 1024 + col - 1024] = f2bf(res);
                }
            }
        }
        return;
    }

    #pragma unroll
    for (int m = 0; m < 4; ++m) {
        int row = bm + wr * 64 + m * 16 + lg * 4;
        #pragma unroll
        for (int n = 0; n < 4; ++n) {
            int col = bn + wc * 64 + n * 16 + lk;
            #pragma unroll
            for (int r = 0; r < 4; ++r) {
                float v = acc[m][n][r];
                if (EPI >= 1) v += bias[col];
                if (EPI == 2) {
                    float u = v * 0.7978845608f * (1.0f + 0.044715f * v * v);
                    v = v / (1.0f + __expf(-2.0f * u));
                }
                if (OUT_BF)
                    ((unsigned short*)Cout)[(size_t)(row + r) * ldc + col] = f2bf(v);
                else
                    ((float*)Cout)[(size_t)(row + r) * ldc + col] = v;
            }
        }
    }
}

// ---------------------------------------------------------------------------
__global__ __launch_bounds__(256) void cvt_bf16(
    const float* __restrict__ src, unsigned short* __restrict__ dst, int n)
{
    int i = (blockIdx.x * 256 + threadIdx.x) * 4;
    if (i < n) {
        float4 v = *(const float4*)(src + i);
        u16x4 o = { f2bf(v.x), f2bf(v.y), f2bf(v.z), f2bf(v.w) };
        *(u16x4*)(dst + i) = o;
    }
}

// ---------------------------------------------------------------------------
__global__ __launch_bounds__(256) void transpose_cvt(
    const float* __restrict__ src, unsigned short* __restrict__ dst, int R, int Cc)
{
    __shared__ float t[32][33];
    const int bc = blockIdx.x * 32, br = blockIdx.y * 32;
    const int tx = threadIdx.x & 31, ty = threadIdx.x >> 5;
    #pragma unroll
    for (int i = 0; i < 4; ++i)
        t[ty + i * 8][tx] = src[(size_t)(br + ty + i * 8) * Cc + bc + tx];
    __syncthreads();
    #pragma unroll
    for (int i = 0; i < 4; ++i)
        dst[(size_t)(bc + ty + i * 8) * R + br + tx] = f2bf(t[tx][ty + i * 8]);
}

// ---------------------------------------------------------------------------
// Flash attention, swapped-operand (r14) + defer-max/setprio (r16) +
// r17: QBLK=128 — two 64-row q-tiles share each K/V staging (staging cost
// per unit FLOP halves). Ps reuse across the two q-passes is in-wave safe
// (pf ds_reads complete before next pass's ds_writes in program order).
// ---------------------------------------------------------------------------
__global__ __launch_bounds__(256, 4) void attn_mfma(
    const unsigned short* __restrict__ Q, const unsigned short* __restrict__ K,
    const unsigned short* __restrict__ V, unsigned short* __restrict__ O,
    int B, int H, int N)
{
    __shared__ unsigned short Ks[64 * 64];
    __shared__ unsigned short Vt[64 * 72];
    __shared__ unsigned short Ps[4][16 * 72];

    const int bi = blockIdx.x;                  // 1024 blocks
    const int bh = (bi & 7) + 8 * ((bi >> 3) & 15);   // same bh -> same XCD
    const int q0 = (bi >> 7) * 128;
    const int b = bh >> 4, h = bh & 15;
    const int tid = threadIdx.x;
    const int w = tid >> 6, lane = tid & 63;
    const int lg = lane >> 4, lk = lane & 15;

    bf16x8 qf[2][2];                            // [qt][kh]
    #pragma unroll
    for (int qt = 0; qt < 2; ++qt) {
        const unsigned short* qrow =
            Q + (size_t)(b * N + q0 + qt * 64 + w * 16 + lk) * 1024 + h * 64;
        qf[qt][0] = *(const bf16x8*)(qrow + lg * 8);
        qf[qt][1] = *(const bf16x8*)(qrow + 32 + lg * 8);
    }

    f32x4 o[2][4] = {};
    float m_run[2] = { -INFINITY, -INFINITY }, l_run[2] = { 0.f, 0.f };

    for (int t0 = 0; t0 < N; t0 += 64) {
        const size_t kvbase = (size_t)(b * N + t0) * 1024 + h * 64;
        #pragma unroll
        for (int it = 0; it < 2; ++it) {        // K: swizzled-source GLL
            int s = it * 256 + tid;
            int row = s >> 3, cb = (s & 7) << 4;
            int dby = cb ^ ((row & 7) << 4);
            GLL16(K + kvbase + (size_t)row * 1024 + (dby >> 1), &Ks[s * 8]);
        }
        {                                       // V: reg-staged transpose
            int c = tid >> 5, k0 = (tid & 31) * 2;
            const unsigned short* vp = V + kvbase + (size_t)k0 * 1024 + c * 8;
            u16x8 va = *(const u16x8*)vp;
            u16x8 vb = *(const u16x8*)(vp + 1024);
            #pragma unroll
            for (int j = 0; j < 8; ++j) {
                unsigned val = (unsigned)va[j] | ((unsigned)vb[j] << 16);
                *(unsigned*)&Vt[(c * 8 + j) * 72 + k0] = val;
            }
        }
        __syncthreads();

        #pragma unroll
        for (int qt = 0; qt < 2; ++qt) {
            f32x4 s4[4];
            __builtin_amdgcn_s_setprio(1);
            #pragma unroll
            for (int sub = 0; sub < 4; ++sub) {
                f32x4 acc = {0.f, 0.f, 0.f, 0.f};
                #pragma unroll
                for (int kh = 0; kh < 2; ++kh) {
                    int cc = (kh * 64 + lg * 16) ^ ((lk & 7) << 4);
                    bf16x8 kf = *(const bf16x8*)&Ks[(sub * 16 + lk) * 64 + (cc >> 1)];
                    acc = __builtin_amdgcn_mfma_f32_16x16x32_bf16(kf, qf[qt][kh], acc, 0, 0, 0);
                }
                s4[sub] = acc;
            }
            __builtin_amdgcn_s_setprio(0);

            float pmax = -INFINITY;
            #pragma unroll
            for (int sub = 0; sub < 4; ++sub)
                #pragma unroll
                for (int r = 0; r < 4; ++r) pmax = fmaxf(pmax, s4[sub][r]);
            pmax = fmaxf(pmax, __shfl_xor(pmax, 16));
            pmax = fmaxf(pmax, __shfl_xor(pmax, 32));

            if (!__all(pmax - m_run[qt] <= 8.0f)) {   // T13 defer-max
                float mn = fmaxf(m_run[qt], pmax);
                float corr = __expf(m_run[qt] - mn);
                m_run[qt] = mn;
                l_run[qt] *= corr;
                #pragma unroll
                for (int ds = 0; ds < 4; ++ds)
                    #pragma unroll
                    for (int r = 0; r < 4; ++r) o[qt][ds][r] *= corr;
            }

            float psum = 0.f;
            unsigned pw[4][2];
            #pragma unroll
            for (int sub = 0; sub < 4; ++sub) {
                float p0 = __expf(s4[sub][0] - m_run[qt]);
                float p1 = __expf(s4[sub][1] - m_run[qt]);
                float p2 = __expf(s4[sub][2] - m_run[qt]);
                float p3 = __expf(s4[sub][3] - m_run[qt]);
                psum += (p0 + p1) + (p2 + p3);
                pw[sub][0] = (__float_as_uint(p0) >> 16) | (__float_as_uint(p1) & 0xffff0000u);
                pw[sub][1] = (__float_as_uint(p2) >> 16) | (__float_as_uint(p3) & 0xffff0000u);
            }
            psum += __shfl_xor(psum, 16);
            psum += __shfl_xor(psum, 32);
            l_run[qt] += psum;
            #pragma unroll
            for (int sub = 0; sub < 4; ++sub) {
                *(unsigned*)&Ps[w][lk * 72 + sub * 16 + lg * 4]     = pw[sub][0];
                *(unsigned*)&Ps[w][lk * 72 + sub * 16 + lg * 4 + 2] = pw[sub][1];
            }
            asm volatile("s_waitcnt lgkmcnt(0)" ::: "memory");   // per-wave P RAW

            __builtin_amdgcn_s_setprio(1);
            #pragma unroll
            for (int kh = 0; kh < 2; ++kh) {
                bf16x8 pf = *(const bf16x8*)&Ps[w][lk * 72 + kh * 32 + lg * 8];
                #pragma unroll
                for (int ds = 0; ds < 4; ++ds) {
                    bf16x8 vf = *(const bf16x8*)&Vt[(ds * 16 + lk) * 72 + kh * 32 + lg * 8];
                    o[qt][ds] = __builtin_amdgcn_mfma_f32_16x16x32_bf16(vf, pf, o[qt][ds], 0, 0, 0);
                }
            }
            __builtin_amdgcn_s_setprio(0);
        }
        __syncthreads();
    }

    #pragma unroll
    for (int qt = 0; qt < 2; ++qt) {
        unsigned short* orow =
            O + (size_t)(b * N + q0 + qt * 64 + w * 16 + lk) * 1024 + h * 64;
        float rinv = 1.0f / l_run[qt];
        #pragma unroll
        for (int ds = 0; ds < 4; ++ds) {
            u16x4 pk = { f2bf(o[qt][ds][0] * rinv), f2bf(o[qt][ds][1] * rinv),
                         f2bf(o[qt][ds][2] * rinv), f2bf(o[qt][ds][3] * rinv) };
            *(u16x4*)(orow + ds * 16 + lg * 4) = pk;
        }
    }
}

// ---------------------------------------------------------------------------
// Fused residual + LayerNorm: out = LN(x + gamma*bf2f(y)) * w + b
// ---------------------------------------------------------------------------
__global__ __launch_bounds__(256) void ln_res_kernel(
    const float* __restrict__ x, const unsigned short* __restrict__ y,
    const float* __restrict__ gamma, const float* __restrict__ w,
    const float* __restrict__ bia, float* __restrict__ out,
    unsigned short* __restrict__ out_bf, int C)
{
    const int row = blockIdx.x;
    __shared__ float buf[1024];
    __shared__ float red[8];
    const size_t base = (size_t)row * C;
    float s = 0.f, ss = 0.f;
    for (int c = threadIdx.x; c < C; c += 256) {
        float v = x[base + c] + gamma[c] * bf2f(y[base + c]);
        buf[c] = v; s += v; ss += v * v;
    }
    #pragma unroll
    for (int msk = 1; msk < 64; msk <<= 1) { s += __shfl_xor(s, msk); ss += __shfl_xor(ss, msk); }
    int wv = threadIdx.x >> 6, lane = threadIdx.x & 63;
    if (lane == 0) { red[wv * 2] = s; red[wv * 2 + 1] = ss; }
    __syncthreads();
    if (threadIdx.x == 0) {
        float S = 0.f, SS = 0.f;
        #pragma unroll
        for (int i = 0; i < 4; ++i) { S += red[2 * i]; SS += red[2 * i + 1]; }
        red[0] = S; red[1] = SS;
    }
    __syncthreads();
    float mu = red[0] / C;
    float var = red[1] / C - mu * mu;
    float rstd = rsqrtf(var + 1e-5f);
    for (int c = threadIdx.x; c < C; c += 256) {
        float v = (buf[c] - mu) * rstd * w[c] + bia[c];
        out[base + c] = v;
        if (out_bf) out_bf[base + c] = f2bf(v);
    }
}

// ---------------------------------------------------------------------------
extern "C" void kernel_launch(void* const* d_in, const int* in_sizes, int n_in,
                              void* d_out, int out_size, void* d_ws, size_t ws_size,
                              hipStream_t stream)
{
    const float* x      = (const float*)d_in[0];
    const float* demo   = (const float*)d_in[1];
    const float* expl   = (const float*)d_in[2];
    const float* fb     = (const float*)d_in[3];
    const float* w_qkv  = (const float*)d_in[4];
    const float* w_proj = (const float*)d_in[5];
    const float* b_proj = (const float*)d_in[6];
    const float* gamma1 = (const float*)d_in[7];
    const float* gamma2 = (const float*)d_in[8];
    const float* ln1_w  = (const float*)d_in[9];
    const float* ln1_b  = (const float*)d_in[10];
    const float* ln2_w  = (const float*)d_in[11];
    const float* ln2_b  = (const float*)d_in[12];
    const float* w1     = (const float*)d_in[13];
    const float* b1     = (const float*)d_in[14];
    const float* w2     = (const float*)d_in[15];
    const float* b2     = (const float*)d_in[16];
    float* out = (float*)d_out;

    const int B = 8, N = 1024, C = 1024, F = 4096, H = 16;
    const int M = B * N;                        // 8192
    const size_t Mi = 1048576;

    float* ws = (float*)d_ws;
    unsigned short* Obf  = (unsigned short*)ws;              // M x 1024 bf16
    unsigned short* H2   = (unsigned short*)ws;              // M x 1024 bf16
    unsigned short* Qbf  = (unsigned short*)(ws + 8 * Mi);   // M x 1024 bf16
    unsigned short* Kbf  = (unsigned short*)(ws + 12 * Mi);
    unsigned short* Vbf  = (unsigned short*)(ws + 16 * Mi);
    unsigned short* Hid  = (unsigned short*)(ws + 8 * Mi);   // M x 4096 bf16
    unsigned short* Ebf  = (unsigned short*)(ws + 24 * Mi);
    unsigned short* Xbf  = (unsigned short*)(ws + 28 * Mi);
    unsigned short* Pb   = (unsigned short*)(ws + 24 * Mi);  // M x 1024 bf16
    float*          X1   = ws + 32 * Mi;                     // M x 1024 f32
    unsigned short* X1bf = (unsigned short*)(ws + 40 * Mi);
    unsigned short* Wt   = (unsigned short*)(ws + 44 * Mi);
    unsigned short* wqkvT  = Wt;                             // [3072][1024]
    unsigned short* wprojT = Wt + (size_t)3145728;           // [1024][1024]
    unsigned short* w1T    = wprojT + (size_t)1048576;       // [4096][1024]
    unsigned short* w2T    = w1T + (size_t)4194304;          // [1024][4096]

    dim3 blk(256);
    const int MC = M * C;

    hipLaunchKernelGGL(cvt_bf16, dim3(MC / 1024), blk, 0, stream, expl, Ebf, MC);
    hipLaunchKernelGGL(cvt_bf16, dim3(MC / 1024), blk, 0, stream, x, Xbf, MC);
    hipLaunchKernelGGL(transpose_cvt, dim3(96, 32), blk, 0, stream, w_qkv, wqkvT, C, 3 * C);
    hipLaunchKernelGGL(transpose_cvt, dim3(32, 32), blk, 0, stream, w_proj, wprojT, C, C);
    hipLaunchKernelGGL(transpose_cvt, dim3(128, 32), blk, 0, stream, w1, w1T, C, F);
    hipLaunchKernelGGL(transpose_cvt, dim3(32, 128), blk, 0, stream, w2, w2T, F, C);

    // QK projection with FUSED drofe -> Qbf (scaled) + Kbf directly
    hipLaunchKernelGGL((gemm2ph128<3,1>), dim3(64 * 16), blk, 0, stream, Ebf, wqkvT,
                       (const float*)nullptr, (void*)Qbf, (void*)Kbf, fb, demo, M, 2048, C, 2048);
    // V projection
    hipLaunchKernelGGL((gemm2ph128<0,1>), dim3(64 * 8), blk, 0, stream, Xbf,
                       wqkvT + (size_t)2048 * 1024, (const float*)nullptr, (void*)Vbf,
                       (void*)nullptr, (const float*)nullptr, (const float*)nullptr, M, 1024, C, 1024);

    // attention (QBLK=128) -> bf16 O
    hipLaunchKernelGGL(attn_mfma, dim3(B * H * (N / 128)), blk, 0, stream, Qbf, Kbf, Vbf, Obf, B, H, N);

    // output projection -> bf16 Pb
    hipLaunchKernelGGL((gemm2ph128<1,1>), dim3(64 * 8), blk, 0, stream, Obf, wprojT, b_proj,
                       (void*)Pb, (void*)nullptr, (const float*)nullptr, (const float*)nullptr, M, 1024, C, 1024);

    // residual + LN1 (f32 + bf16)
    hipLaunchKernelGGL(ln_res_kernel, dim3(M), blk, 0, stream, x, Pb, gamma1, ln1_w, ln1_b, X1, X1bf, C);

    // MLP: MLP1 [fast gelu], MLP2 [K=4096] -> bf16
    hipLaunchKernelGGL((gemm2ph128<2,1>), dim3(64 * 32), blk, 0, stream, X1bf, w1T, b1,
                       (void*)Hid, (void*)nullptr, (const float*)nullptr, (const float*)nullptr, M, F, C, F);
    hipLaunchKernelGGL((gemm2ph128<1,1>), dim3(64 * 8), blk, 0, stream, Hid, w2T, b2,
                       (void*)H2, (void*)nullptr, (const float*)nullptr, (const float*)nullptr, M, 1024, F, 1024);

    // residual + LN2 -> out
    hipLaunchKernelGGL(ln_res_kernel, dim3(M), blk, 0, stream, X1, H2, gamma2, ln2_w, ln2_b, out, (unsigned short*)nullptr, C);
}